// Round 4
// baseline (852.770 us; speedup 1.0000x reference)
//
#include <hip/hip_runtime.h>
#include <hip/hip_bf16.h>

typedef short short8 __attribute__((ext_vector_type(8)));
typedef float floatx4 __attribute__((ext_vector_type(4)));

#define HP 168   // lH1 pitch (bf16): row stride 84 words = 20 mod 32 -> 2-way (free)

__device__ __forceinline__ unsigned short f2bf(float f) {
    __hip_bfloat16 h = __float2bfloat16(f);
    return __builtin_bit_cast(unsigned short, h);
}
__device__ __forceinline__ float bf2f(unsigned short s) {
    __hip_bfloat16 h = __builtin_bit_cast(__hip_bfloat16, s);
    return __bfloat162float(h);
}

// 16-lane row sum via v_add_f32_dpp row_ror — pure VALU, no LDS pipe.
__device__ __forceinline__ float dpp_sum16(float v) {
    v += __builtin_bit_cast(float, __builtin_amdgcn_update_dpp(
             0, __builtin_bit_cast(int, v), 0x128, 0xF, 0xF, true));  // row_ror:8
    v += __builtin_bit_cast(float, __builtin_amdgcn_update_dpp(
             0, __builtin_bit_cast(int, v), 0x124, 0xF, 0xF, true));  // row_ror:4
    v += __builtin_bit_cast(float, __builtin_amdgcn_update_dpp(
             0, __builtin_bit_cast(int, v), 0x122, 0xF, 0xF, true));  // row_ror:2
    v += __builtin_bit_cast(float, __builtin_amdgcn_update_dpp(
             0, __builtin_bit_cast(int, v), 0x121, 0xF, 0xF, true));  // row_ror:1
    return v;
}

// Pack Wc = [w1; wt] (320x320) into B-fragment order for mfma_f32_16x16x32_bf16.
// elem j of lane l for (t,kb): n = t*16+(l&15), k = kb*32+(l>>4)*8+j; flat (((t*10+kb)*64+l)*8+j)
__global__ void pack_wc(const float* __restrict__ w1, const float* __restrict__ wt,
                        unsigned short* __restrict__ dst) {
    int i = blockIdx.x * 256 + threadIdx.x;
    if (i >= 320 * 320) return;
    int j = i & 7;
    int lane = (i >> 3) & 63;
    int r = i >> 9;
    int kb = r % 10;
    int t = r / 10;
    int n = t * 16 + (lane & 15);
    int k = kb * 32 + ((lane >> 4) << 3) + j;
    float v = (n < 160) ? w1[n * 320 + k] : wt[(n - 160) * 320 + k];
    dst[i] = f2bf(v);
}

__global__ void pack_w2(const float* __restrict__ w2, unsigned short* __restrict__ dst) {
    int i = blockIdx.x * 256 + threadIdx.x;
    if (i >= 160 * 160) return;
    int j = i & 7;
    int lane = (i >> 3) & 63;
    int r = i >> 9;
    int kb = r % 5;
    int t = r / 5;
    int n = t * 16 + (lane & 15);
    int k = kb * 32 + ((lane >> 4) << 3) + j;
    dst[i] = f2bf(w2[n * 160 + k]);
}

// 64-row / 8-wave (512-thread) blocks. launch_bounds(512,4): 128-reg cap -> 16 waves/CU,
// 2 independent blocks/CU. Per-wave acc = 40 regs (GEMM1 2m x 4n split) -> no spills.
// GEMM1 wave (wm1 = w&1 row-half, wn1 = w>>1 n-quarter). waves wn1>=2 own ht and keep
// 16 rows x 80 ch in registers (hk); the other 16-row group goes to lHT (10,240 B).
// GEMM2 wave (mq row-quarter, nh col-half) chosen so keepers consume their own hk.
__global__ __launch_bounds__(512, 4) void fused_kernel(
    const float* __restrict__ actors, const float* __restrict__ paths,
    const float* __restrict__ Z_act, const float* __restrict__ Z_pat,
    const int* __restrict__ u,
    const unsigned short* __restrict__ pB1, const unsigned short* __restrict__ pB2,
    const float* __restrict__ g1w, const float* __restrict__ g1b,
    const float* __restrict__ g2w, const float* __restrict__ g2b,
    const float* __restrict__ wh, const float* __restrict__ bh,
    float* __restrict__ out)
{
    // Phase 1: lX [0,40960) — X in MFMA A-fragment order, XOR-swizzled slots:
    //   shorts addr = ((mt*10+kb)*64 + slot)*8, slot = ((r&15)|(qd<<4)) ^ ((qd^kb)&7)
    // Phase 2 (aliases lX): lH1 [0,21504) 64xHP row-major; lHT [21504,31744)
    //   [4 grp][80 ch][4 quad] ushort4; sP [31744,32768) float2[2][64]; sDp [32768,33280).
    __shared__ __align__(16) char smem[40960];
    unsigned short* lX  = (unsigned short*)smem;
    unsigned short* lH1 = (unsigned short*)smem;
    unsigned short* lHT = (unsigned short*)(smem + 21504);
    float2* sP  = (float2*)(smem + 31744);
    float*  sDp = (float*)(smem + 32768);

    const int tid  = threadIdx.x;     // 0..511
    const int w    = tid >> 6;        // 0..7
    const int lane = tid & 63;
    const int quad = lane >> 4;
    const int l15  = lane & 15;
    const int row0 = blockIdx.x * 64;

    const int wm1 = w & 1;            // GEMM1 row-half (32 rows)
    const int wn1 = w >> 1;           // GEMM1 n-quarter (80 cols)
    const int nh  = (w >> 1) & 1;     // GEMM2 col-half (80 ch)
    const int mq  = (w & 1) * 2 + ((w < 4) ? (1 - (w >> 1)) : ((w >> 1) - 2)); // GEMM2 row-quarter

    // ================= staging: 2560 direct + 2560 gather sub-granules (4 floats) ========
    float4 vD[5], vG[5];
    int uv[5], rr[5], qq[5];
    #pragma unroll
    for (int i = 0; i < 5; i++) {     // phase A: direct loads + u loads
        int f = i * 512 + tid;
        int r = f / 40, sq = f - r * 40;
        rr[i] = r; qq[i] = sq;
        const float* src = (sq < 32) ? (paths + (size_t)(row0 + r) * 128 + sq * 4)
                                     : (Z_pat + (size_t)(row0 + r) * 32 + (sq - 32) * 4);
        vD[i] = *(const float4*)src;
        uv[i] = u[row0 + r];
    }
    #pragma unroll
    for (int i = 0; i < 5; i++) {     // phase B: dependent gather loads
        int sq = qq[i];
        int un = uv[i];
        const float* src = (sq < 32) ? (actors + (size_t)un * 128 + sq * 4)
                                     : (Z_act + (size_t)un * 32 + (sq - 32) * 4);
        vG[i] = *(const float4*)src;
    }
    #pragma unroll
    for (int i = 0; i < 5; i++) {     // phase C: convert + fragment-order LDS write (b64)
        int r = rr[i], sq = qq[i];
        int mt = r >> 4;
        int g = sq >> 1, h = sq & 1;
        {   // direct granule: k = g*8 + h*4 ..
            int kb = g >> 2, qd = g & 3;
            int slot = ((r & 15) | (qd << 4)) ^ ((qd ^ kb) & 7);
            ushort4 sv;
            sv.x = f2bf(vD[i].x); sv.y = f2bf(vD[i].y);
            sv.z = f2bf(vD[i].z); sv.w = f2bf(vD[i].w);
            *(ushort4*)(lX + ((mt * 10 + kb) * 64 + slot) * 8 + h * 4) = sv;
        }
        {   // gather granule: k = 160 + g*8 + h*4 ..
            int g8 = g + 20;
            int kb = g8 >> 2, qd = g8 & 3;
            int slot = ((r & 15) | (qd << 4)) ^ ((qd ^ kb) & 7);
            ushort4 sv;
            sv.x = f2bf(vG[i].x); sv.y = f2bf(vG[i].y);
            sv.z = f2bf(vG[i].z); sv.w = f2bf(vG[i].w);
            *(ushort4*)(lX + ((mt * 10 + kb) * 64 + slot) * 8 + h * 4) = sv;
        }
    }

    // GEMM1 B prologue: kb=0,1 (independent of LDS)
    const unsigned short* pBw = pB1 + (size_t)wn1 * 25600 + (size_t)lane * 8;
    short8 bA[5], bB[5];
    #pragma unroll
    for (int ti = 0; ti < 5; ti++) {
        bA[ti] = *(const short8*)(pBw + (size_t)(ti * 10 + 0) * 512);
        bB[ti] = *(const short8*)(pBw + (size_t)(ti * 10 + 1) * 512);
    }
    __syncthreads();   // B1: lX ready

    // ================= GEMM1: C[64x320] = X @ [w1;wt]^T; wave = (wm1, wn1) ==============
    floatx4 fzero = {0.f, 0.f, 0.f, 0.f};
    floatx4 acc[2][5];
    #pragma unroll
    for (int i = 0; i < 2; i++)
        #pragma unroll
        for (int j = 0; j < 5; j++) acc[i][j] = fzero;

    #pragma unroll
    for (int kb = 0; kb < 10; kb++) {
        int sl = (lane ^ ((quad ^ kb) & 7)) * 8;
        short8 a0 = *(const short8*)(lX + ((wm1 * 2 + 0) * 10 + kb) * 512 + sl);
        short8 a1 = *(const short8*)(lX + ((wm1 * 2 + 1) * 10 + kb) * 512 + sl);
        short8 bN[5];
        if (kb + 2 < 10) {
            #pragma unroll
            for (int ti = 0; ti < 5; ti++)
                bN[ti] = *(const short8*)(pBw + (size_t)(ti * 10 + kb + 2) * 512);
        }
        #pragma unroll
        for (int ti = 0; ti < 5; ti++) {
            acc[0][ti] = __builtin_amdgcn_mfma_f32_16x16x32_bf16(a0, bA[ti], acc[0][ti], 0, 0, 0);
            acc[1][ti] = __builtin_amdgcn_mfma_f32_16x16x32_bf16(a1, bA[ti], acc[1][ti], 0, 0, 0);
        }
        #pragma unroll
        for (int ti = 0; ti < 5; ti++) { bA[ti] = bB[ti]; bB[ti] = bN[ti]; }
    }
    __syncthreads();   // B2: lX dead; lH1/lHT/sP region live

    // ================= post-GEMM1 split =================================================
    ushort4 hk[5];     // keepers (w>=4): 16 rows x 80 ch of ht in regs
    if (w >= 4) {
        int mt_keep = wn1 - 2;          // w4,w5 -> 0; w6,w7 -> 1 (matches mq rows)
        int mt_store = 1 - mt_keep;
        int grp = w - 4;
        #pragma unroll
        for (int ti = 0; ti < 5; ti++) {
            ushort4 kv;
            kv.x = f2bf(acc[mt_keep][ti][0]); kv.y = f2bf(acc[mt_keep][ti][1]);
            kv.z = f2bf(acc[mt_keep][ti][2]); kv.w = f2bf(acc[mt_keep][ti][3]);
            hk[ti] = kv;
            ushort4 sv;
            sv.x = f2bf(acc[mt_store][ti][0]); sv.y = f2bf(acc[mt_store][ti][1]);
            sv.z = f2bf(acc[mt_store][ti][2]); sv.w = f2bf(acc[mt_store][ti][3]);
            int idx = (grp * 80 + ti * 16 + l15) * 4 + quad;
            *(ushort4*)(lHT + idx * 4) = sv;
        }
    } else {
        // GN1 partial stats: this wave covers ch [wn1*80, wn1*80+80) of rows wm1-half
        #pragma unroll
        for (int mt = 0; mt < 2; mt++)
            #pragma unroll
            for (int r = 0; r < 4; r++) {
                float s = 0.f, q2 = 0.f;
                #pragma unroll
                for (int ti = 0; ti < 5; ti++) {
                    float v = acc[mt][ti][r];
                    s += v; q2 += v * v;
                }
                s = dpp_sum16(s); q2 = dpp_sum16(q2);
                if (l15 == 0) {
                    int row = wm1 * 32 + mt * 16 + quad * 4 + r;
                    float2 pv; pv.x = s; pv.y = q2;
                    sP[wn1 * 64 + row] = pv;
                }
            }
    }
    __syncthreads();   // B3: GN1 partials + lHT ready

    // GEMM2 B prologue: kb=0,1 (independent of LDS)
    const unsigned short* pB2w = pB2 + (size_t)nh * 12800 + (size_t)lane * 8;
    short8 b2A[5], b2B[5];
    #pragma unroll
    for (int ti = 0; ti < 5; ti++) {
        b2A[ti] = *(const short8*)(pB2w + (size_t)(ti * 5 + 0) * 512);
        b2B[ti] = *(const short8*)(pB2w + (size_t)(ti * 5 + 1) * 512);
    }

    // ================= GN1 apply + ReLU + write lH1 (waves 0..3) ========================
    if (w < 4) {
        float gw[5], gb[5];
        #pragma unroll
        for (int ti = 0; ti < 5; ti++) {
            int n = wn1 * 80 + ti * 16 + l15;
            gw[ti] = g1w[n]; gb[ti] = g1b[n];
        }
        #pragma unroll
        for (int mt = 0; mt < 2; mt++)
            #pragma unroll
            for (int r = 0; r < 4; r++) {
                int row = wm1 * 32 + mt * 16 + quad * 4 + r;
                float2 p0 = sP[row];
                float2 p1 = sP[64 + row];
                float mu = (p0.x + p1.x) * (1.f / 160.f);
                float var = (p0.y + p1.y) * (1.f / 160.f) - mu * mu;
                float rs = rsqrtf(var + 1e-5f);
                #pragma unroll
                for (int ti = 0; ti < 5; ti++) {
                    float v = (acc[mt][ti][r] - mu) * rs * gw[ti] + gb[ti];
                    v = fmaxf(v, 0.f);
                    lH1[row * HP + wn1 * 80 + ti * 16 + l15] = f2bf(v);
                }
            }
    }
    __syncthreads();   // B4: lH1 ready (also separates sP GN1-reads from GN2-writes)

    // ================= GEMM2: h2[64x160] = h1 @ w2^T; wave = (mq, nh) ===================
    floatx4 acc2[5];
    #pragma unroll
    for (int j = 0; j < 5; j++) acc2[j] = fzero;

    #pragma unroll
    for (int kb = 0; kb < 5; kb++) {
        short8 a = *(const short8*)(lH1 + (mq * 16 + l15) * HP + kb * 32 + quad * 8);
        short8 bN[5];
        if (kb + 2 < 5) {
            #pragma unroll
            for (int ti = 0; ti < 5; ti++)
                bN[ti] = *(const short8*)(pB2w + (size_t)(ti * 5 + kb + 2) * 512);
        }
        #pragma unroll
        for (int ti = 0; ti < 5; ti++)
            acc2[ti] = __builtin_amdgcn_mfma_f32_16x16x32_bf16(a, b2A[ti], acc2[ti], 0, 0, 0);
        #pragma unroll
        for (int ti = 0; ti < 5; ti++) { b2A[ti] = b2B[ti]; b2B[ti] = bN[ti]; }
    }

    // ================= GN2 partial stats (80-ch half per wave) ==========================
    #pragma unroll
    for (int r = 0; r < 4; r++) {
        float s = 0.f, q2 = 0.f;
        #pragma unroll
        for (int ti = 0; ti < 5; ti++) {
            float v = acc2[ti][r];
            s += v; q2 += v * v;
        }
        s = dpp_sum16(s); q2 = dpp_sum16(q2);
        if (l15 == 0) {
            int row = mq * 16 + quad * 4 + r;
            float2 pv; pv.x = s; pv.y = q2;
            sP[nh * 64 + row] = pv;
        }
    }
    __syncthreads();   // B5: GN2 partials ready

    // ================= GN2 apply + skip(ht) + ReLU + head dot ===========================
    {
        float mu2[4], rs2[4];
        #pragma unroll
        for (int r = 0; r < 4; r++) {
            int row = mq * 16 + quad * 4 + r;
            float2 p0 = sP[row];
            float2 p1 = sP[64 + row];
            float mu = (p0.x + p1.x) * (1.f / 160.f);
            float var = (p0.y + p1.y) * (1.f / 160.f) - mu * mu;
            mu2[r] = mu;
            rs2[r] = rsqrtf(var + 1e-5f);
        }
        float g2wv[5], g2bv[5], whv[5];
        #pragma unroll
        for (int ti = 0; ti < 5; ti++) {
            int n = nh * 80 + ti * 16 + l15;
            g2wv[ti] = g2w[n]; g2bv[ti] = g2b[n]; whv[ti] = wh[n];
        }
        float dp[4];
        #pragma unroll
        for (int r = 0; r < 4; r++) dp[r] = 0.f;

        int grp = nh * 2 + wm1;   // lHT group for non-keepers
        #pragma unroll
        for (int ti = 0; ti < 5; ti++) {
            ushort4 hv;
            if (w >= 4) {
                hv = hk[ti];
            } else {
                int idx = (grp * 80 + ti * 16 + l15) * 4 + quad;
                hv = *(const ushort4*)(lHT + idx * 4);
            }
            float hvf[4];
            hvf[0] = bf2f(hv.x); hvf[1] = bf2f(hv.y);
            hvf[2] = bf2f(hv.z); hvf[3] = bf2f(hv.w);
            #pragma unroll
            for (int r = 0; r < 4; r++) {
                float v = (acc2[ti][r] - mu2[r]) * rs2[r] * g2wv[ti] + g2bv[ti];
                v += hvf[r];
                v = fmaxf(v, 0.f);
                dp[r] += v * whv[ti];
            }
        }
        #pragma unroll
        for (int r = 0; r < 4; r++) dp[r] = dpp_sum16(dp[r]);
        if (l15 == 0) {
            #pragma unroll
            for (int r = 0; r < 4; r++) {
                int row = mq * 16 + quad * 4 + r;
                sDp[nh * 64 + row] = dp[r];
            }
        }
    }
    __syncthreads();   // B6: dp halves ready
    if (tid < 64) out[row0 + tid] = sDp[tid] + sDp[64 + tid] + bh[0];
}

extern "C" void kernel_launch(void* const* d_in, const int* in_sizes, int n_in,
                              void* d_out, int out_size, void* d_ws, size_t ws_size,
                              hipStream_t stream) {
    const float* actors = (const float*)d_in[0];
    const float* paths  = (const float*)d_in[1];
    const float* Z_act  = (const float*)d_in[2];
    const float* Z_pat  = (const float*)d_in[3];
    const int*   u      = (const int*)d_in[4];
    const float* w1     = (const float*)d_in[5];
    const float* w2     = (const float*)d_in[6];
    const float* wt     = (const float*)d_in[7];
    const float* g1w    = (const float*)d_in[8];
    const float* g1b    = (const float*)d_in[9];
    const float* g2w    = (const float*)d_in[10];
    const float* g2b    = (const float*)d_in[11];
    const float* wh     = (const float*)d_in[12];
    const float* bh     = (const float*)d_in[13];
    float* out = (float*)d_out;

    unsigned short* pB1 = (unsigned short*)d_ws;
    unsigned short* pB2 = pB1 + 320 * 320;

    hipLaunchKernelGGL(pack_wc, dim3(400), dim3(256), 0, stream, w1, wt, pB1);
    hipLaunchKernelGGL(pack_w2, dim3(100), dim3(256), 0, stream, w2, pB2);
    hipLaunchKernelGGL(fused_kernel, dim3(400000 / 64), dim3(512), 0, stream,
                       actors, paths, Z_act, Z_pat, u, pB1, pB2,
                       g1w, g1b, g2w, g2b, wh, bh, out);
}